// Round 3
// baseline (1126.333 us; speedup 1.0000x reference)
//
#include <hip/hip_runtime.h>

#define N_NODES 50000
#define E_EDGES 600000
#define D_IN 128
#define O_OUT 128
#define R_REL 8
#define B_BAS 4
#define NCT 1152   // R*O (per-relation outputs) + O (self-loop)

typedef __attribute__((ext_vector_type(8))) short bf16x8;
typedef __attribute__((ext_vector_type(4))) float f32x4;

static __device__ __forceinline__ unsigned short f2bf(float f) {
    unsigned int u = __float_as_uint(f);
    unsigned int r = (u + 0x7fffu + ((u >> 16) & 1u)) >> 16;
    return (unsigned short)r;
}
static __device__ __forceinline__ float bf2f(unsigned short b) {
    return __uint_as_float(((unsigned int)b) << 16);
}

// x fp32 [N,128] -> xb bf16 [N,128]
__global__ void convert_x_kernel(const float* __restrict__ x, unsigned short* __restrict__ xb) {
    int i = (blockIdx.x * 256 + threadIdx.x) * 4;  // over N*D
    float4 v = *(const float4*)&x[i];
    ushort4 o;
    o.x = f2bf(v.x); o.y = f2bf(v.y); o.z = f2bf(v.z); o.w = f2bf(v.w);
    *(ushort4*)&xb[i] = o;
}

// Wt [1152][128] bf16 (n-major, k contiguous):
//   j<1024: r=j>>7, o=j&127: Wt[j][d] = sum_b coeffs[r,b]*basis_v[b,d,o]
//   j>=1024: Wt[j][d] = w_loop[d][j-1024]
__global__ void build_wt_kernel(const float* __restrict__ basis_v,
                                const float* __restrict__ coeffs,
                                const float* __restrict__ w_loop,
                                unsigned short* __restrict__ Wt) {
    int i = blockIdx.x * 256 + threadIdx.x;  // over 1152*128
    int j = i >> 7, d = i & 127;
    float v;
    if (j < R_REL * O_OUT) {
        int r = j >> 7, o = j & 127;
        v = coeffs[r * B_BAS + 0] * basis_v[0 * D_IN * O_OUT + d * O_OUT + o]
          + coeffs[r * B_BAS + 1] * basis_v[1 * D_IN * O_OUT + d * O_OUT + o]
          + coeffs[r * B_BAS + 2] * basis_v[2 * D_IN * O_OUT + d * O_OUT + o]
          + coeffs[r * B_BAS + 3] * basis_v[3 * D_IN * O_OUT + d * O_OUT + o];
    } else {
        v = w_loop[d * O_OUT + (j - R_REL * O_OUT)];
    }
    Wt[j * D_IN + d] = f2bf(v);
}

// Per-(relation,dst) in-degree
__global__ void deg_kernel(const int* __restrict__ rel, const int* __restrict__ dst,
                           float* __restrict__ deg) {
    int e = blockIdx.x * 256 + threadIdx.x;
    if (e >= E_EDGES) return;
    atomicAdd(&deg[rel[e] * N_NODES + dst[e]], 1.0f);
}

// Ct[N,1152]bf16 = xb[N,128] @ Wt^T  (MFMA bf16 16x16x32, 128x128 tiles)
__global__ __launch_bounds__(256) void gemm_kernel(const unsigned short* __restrict__ xb,
                                                   const unsigned short* __restrict__ Wt,
                                                   unsigned short* __restrict__ Ct) {
    __shared__ short As[128 * 136];   // A[row][k], row stride 136 bf16 (2-way max on b128)
    __shared__ short Bst[128 * 136];  // B^T[n][k], same stride
    const int col0 = blockIdx.x * 128;  // 9 col tiles
    const int row0 = blockIdx.y * 128;  // 391 row tiles
    const int t = threadIdx.x;

    // stage A: 128 rows x 128 k of bf16 = 32 KB, 16 B per thread per iter
    #pragma unroll
    for (int i = 0; i < 8; ++i) {
        int flat = i * 256 + t;          // 2048 chunks of 16B
        int r = flat >> 4, c16 = flat & 15;
        int4 v = make_int4(0, 0, 0, 0);
        if (row0 + r < N_NODES) v = *(const int4*)&xb[(size_t)(row0 + r) * D_IN + c16 * 8];
        *(int4*)&As[r * 136 + c16 * 8] = v;
    }
    // stage B^T: rows col0..col0+127 of Wt (always in-bounds; 1152 % 128 == 0)
    #pragma unroll
    for (int i = 0; i < 8; ++i) {
        int flat = i * 256 + t;
        int r = flat >> 4, c16 = flat & 15;
        int4 v = *(const int4*)&Wt[(size_t)(col0 + r) * D_IN + c16 * 8];
        *(int4*)&Bst[r * 136 + c16 * 8] = v;
    }
    __syncthreads();

    const int w = t >> 6, l = t & 63;
    const int m0 = w * 32;               // wave owns 32 rows x 128 cols
    const int lr = l & 15, lg = l >> 4;  // lane row/col within frag, k-group

    f32x4 acc[2][8] = {};
    #pragma unroll
    for (int ks = 0; ks < 4; ++ks) {
        const int kb = ks * 32 + lg * 8;
        bf16x8 a0 = *(const bf16x8*)&As[(m0 + lr) * 136 + kb];
        bf16x8 a1 = *(const bf16x8*)&As[(m0 + 16 + lr) * 136 + kb];
        #pragma unroll
        for (int jn = 0; jn < 8; ++jn) {
            bf16x8 b = *(const bf16x8*)&Bst[(jn * 16 + lr) * 136 + kb];
            acc[0][jn] = __builtin_amdgcn_mfma_f32_16x16x32_bf16(a0, b, acc[0][jn], 0, 0, 0);
            acc[1][jn] = __builtin_amdgcn_mfma_f32_16x16x32_bf16(a1, b, acc[1][jn], 0, 0, 0);
        }
    }

    // epilogue: C/D layout col=lane&15, row=(lane>>4)*4+i  [m89-verified]
    #pragma unroll
    for (int im = 0; im < 2; ++im) {
        #pragma unroll
        for (int i = 0; i < 4; ++i) {
            int row = row0 + m0 + im * 16 + lg * 4 + i;
            if (row < N_NODES) {
                #pragma unroll
                for (int jn = 0; jn < 8; ++jn)
                    Ct[(size_t)row * NCT + col0 + jn * 16 + lr] = f2bf(acc[im][jn][i]);
            }
        }
    }
}

// Per edge: gather Ct row (src, rel) [128 bf16], scale by inv_deg, atomic add to out[dst]
// 32 lanes per edge, 4 outputs per lane; 8 edges per block.
__global__ __launch_bounds__(256) void scatter_kernel(const int* __restrict__ src,
                                                      const int* __restrict__ dst,
                                                      const int* __restrict__ rel,
                                                      const unsigned short* __restrict__ Ct,
                                                      const float* __restrict__ deg,
                                                      float* __restrict__ out) {
    int e = blockIdx.x * 8 + (threadIdx.x >> 5);
    int q = threadIdx.x & 31;
    int s = src[e], d = dst[e], r = rel[e];
    float inv = 1.0f / fmaxf(deg[r * N_NODES + d], 1.0f);
    const unsigned short* row = Ct + (size_t)s * NCT + r * O_OUT;
    uint2 v = *(const uint2*)(row + q * 4);
    float f0 = __uint_as_float((v.x & 0xffffu) << 16);
    float f1 = __uint_as_float(v.x & 0xffff0000u);
    float f2 = __uint_as_float((v.y & 0xffffu) << 16);
    float f3 = __uint_as_float(v.y & 0xffff0000u);
    float* o = out + (size_t)d * O_OUT + q * 4;
    atomicAdd(o + 0, f0 * inv);
    atomicAdd(o + 1, f1 * inv);
    atomicAdd(o + 2, f2 * inv);
    atomicAdd(o + 3, f3 * inv);
}

// out = relu(agg + selfloop_cols(bf16) + bias)
__global__ void final_kernel(const unsigned short* __restrict__ Ct,
                             const float* __restrict__ bias,
                             float* __restrict__ out) {
    int i = blockIdx.x * 256 + threadIdx.x;  // over N*O
    int n = i >> 7, o = i & 127;
    float v = out[i] + bf2f(Ct[(size_t)n * NCT + R_REL * O_OUT + o]) + bias[o];
    out[i] = fmaxf(v, 0.0f);
}

extern "C" void kernel_launch(void* const* d_in, const int* in_sizes, int n_in,
                              void* d_out, int out_size, void* d_ws, size_t ws_size,
                              hipStream_t stream) {
    (void)in_sizes; (void)n_in; (void)out_size; (void)ws_size;
    const float* x       = (const float*)d_in[0];
    const float* basis_v = (const float*)d_in[1];
    const float* coeffs  = (const float*)d_in[2];
    const float* w_loop  = (const float*)d_in[3];
    const float* bias_p  = (const float*)d_in[4];
    const int*   src     = (const int*)d_in[5];
    const int*   dst     = (const int*)d_in[6];
    const int*   rel     = (const int*)d_in[7];
    float* out = (float*)d_out;

    char* ws = (char*)d_ws;
    unsigned short* xb = (unsigned short*)ws;                      // 12,800,000 B
    unsigned short* Wt = (unsigned short*)(ws + 12800000);         //    294,912 B
    unsigned short* Ct = (unsigned short*)(ws + 13094912);         // 115,200,000 B
    float*          deg = (float*)(ws + 128294912);                //  1,600,000 B

    hipMemsetAsync(out, 0, (size_t)N_NODES * O_OUT * sizeof(float), stream);
    hipMemsetAsync(deg, 0, (size_t)R_REL * N_NODES * sizeof(float), stream);

    convert_x_kernel<<<N_NODES * D_IN / 1024, 256, 0, stream>>>(x, xb);
    build_wt_kernel<<<NCT * D_IN / 256, 256, 0, stream>>>(basis_v, coeffs, w_loop, Wt);
    deg_kernel<<<(E_EDGES + 255) / 256, 256, 0, stream>>>(rel, dst, deg);
    gemm_kernel<<<dim3(NCT / 128, (N_NODES + 127) / 128), 256, 0, stream>>>(xb, Wt, Ct);
    scatter_kernel<<<E_EDGES / 8, 256, 0, stream>>>(src, dst, rel, Ct, deg, out);
    final_kernel<<<N_NODES * O_OUT / 256, 256, 0, stream>>>(Ct, bias_p, out);
}

// Round 4
// 221.826 us; speedup vs baseline: 5.0776x; 5.0776x over previous
//
#include <hip/hip_runtime.h>

#define N_NODES 50000
#define E_EDGES 600000
#define D_IN 128
#define O_OUT 128
#define R_REL 8
#define B_BAS 4
#define NCT 1152     // R*O (per-relation outputs) + O (self-loop)
#define NB_SCAN 196  // ceil(50000/256)

typedef __attribute__((ext_vector_type(8))) short bf16x8;
typedef __attribute__((ext_vector_type(4))) float f32x4;

static __device__ __forceinline__ unsigned short f2bf(float f) {
    unsigned int u = __float_as_uint(f);
    unsigned int r = (u + 0x7fffu + ((u >> 16) & 1u)) >> 16;
    return (unsigned short)r;
}
static __device__ __forceinline__ float bf2f(unsigned short b) {
    return __uint_as_float(((unsigned int)b) << 16);
}

// Wt [1152][128] bf16 (n-major, k contiguous):
//   j<1024: r=j>>7, o=j&127: Wt[j][d] = sum_b coeffs[r,b]*basis_v[b,d,o]
//   j>=1024: Wt[j][d] = w_loop[d][j-1024]
__global__ void build_wt_kernel(const float* __restrict__ basis_v,
                                const float* __restrict__ coeffs,
                                const float* __restrict__ w_loop,
                                unsigned short* __restrict__ Wt) {
    int i = blockIdx.x * 256 + threadIdx.x;  // over 1152*128
    int j = i >> 7, d = i & 127;
    float v;
    if (j < R_REL * O_OUT) {
        int r = j >> 7, o = j & 127;
        v = coeffs[r * B_BAS + 0] * basis_v[0 * D_IN * O_OUT + d * O_OUT + o]
          + coeffs[r * B_BAS + 1] * basis_v[1 * D_IN * O_OUT + d * O_OUT + o]
          + coeffs[r * B_BAS + 2] * basis_v[2 * D_IN * O_OUT + d * O_OUT + o]
          + coeffs[r * B_BAS + 3] * basis_v[3 * D_IN * O_OUT + d * O_OUT + o];
    } else {
        v = w_loop[d * O_OUT + (j - R_REL * O_OUT)];
    }
    Wt[j * D_IN + d] = f2bf(v);
}

// Per-(relation,dst) in-degree
__global__ void deg_kernel(const int* __restrict__ rel, const int* __restrict__ dst,
                           float* __restrict__ deg) {
    int e = blockIdx.x * 256 + threadIdx.x;
    if (e >= E_EDGES) return;
    atomicAdd(&deg[rel[e] * N_NODES + dst[e]], 1.0f);
}

// scan1: per-dst total count (sum over rel of deg) + per-block exclusive scan
__global__ void scan1_kernel(const float* __restrict__ deg, int* __restrict__ cnt,
                             int* __restrict__ exoff, int* __restrict__ bsum) {
    __shared__ int s[256];
    int t = threadIdx.x;
    int i = blockIdx.x * 256 + t;
    int c = 0;
    if (i < N_NODES) {
        float f = 0.f;
        #pragma unroll
        for (int r = 0; r < R_REL; ++r) f += deg[r * N_NODES + i];
        c = (int)(f + 0.5f);
        cnt[i] = c;
    }
    s[t] = c;
    __syncthreads();
    #pragma unroll
    for (int off = 1; off < 256; off <<= 1) {
        int add = (t >= off) ? s[t - off] : 0;
        __syncthreads();
        s[t] += add;
        __syncthreads();
    }
    if (i < N_NODES) exoff[i] = s[t] - c;
    if (t == 255) bsum[blockIdx.x] = s[255];
}

// scan2: scan the 196 block sums (single block)
__global__ void scan2_kernel(const int* __restrict__ bsum, int* __restrict__ bbase) {
    __shared__ int s[256];
    int t = threadIdx.x;
    int c = (t < NB_SCAN) ? bsum[t] : 0;
    s[t] = c;
    __syncthreads();
    #pragma unroll
    for (int off = 1; off < 256; off <<= 1) {
        int add = (t >= off) ? s[t - off] : 0;
        __syncthreads();
        s[t] += add;
        __syncthreads();
    }
    if (t < NB_SCAN) bbase[t] = s[t] - c;
}

// scan3: offs = exoff + bbase; cursor = copy for atomic slot allocation
__global__ void scan3_kernel(const int* __restrict__ exoff, const int* __restrict__ bbase,
                             int* __restrict__ offs, int* __restrict__ cursor) {
    int i = blockIdx.x * 256 + threadIdx.x;
    if (i >= N_NODES) return;
    int v = exoff[i] + bbase[i >> 8];
    offs[i] = v;
    cursor[i] = v;
}

// fill: slot each edge into its dst bucket; payload = {Ct dword offset, inv_deg}
__global__ void fill_kernel(const int* __restrict__ src, const int* __restrict__ dst,
                            const int* __restrict__ rel, const float* __restrict__ deg,
                            int* __restrict__ cursor, uint2* __restrict__ epack) {
    int e = blockIdx.x * 256 + threadIdx.x;
    if (e >= E_EDGES) return;
    int s = src[e], d = dst[e], r = rel[e];
    int pos = atomicAdd(&cursor[d], 1);
    float inv = 1.0f / fmaxf(deg[r * N_NODES + d], 1.0f);
    epack[pos] = make_uint2((unsigned)(s * NCT + r * O_OUT), __float_as_uint(inv));
}

// Ct[N,1152]bf16 = x[N,128] @ Wt^T  (MFMA bf16 16x16x32, 128x128 tiles; A converted in-stage)
__global__ __launch_bounds__(256) void gemm_kernel(const float* __restrict__ x,
                                                   const unsigned short* __restrict__ Wt,
                                                   unsigned short* __restrict__ Ct) {
    __shared__ short As[128 * 136];   // A[row][k], row stride 136 bf16
    __shared__ short Bst[128 * 136];  // B^T[n][k], same stride
    const int col0 = blockIdx.x * 128;  // 9 col tiles
    const int row0 = blockIdx.y * 128;  // 391 row tiles
    const int t = threadIdx.x;

    // stage A: 128 rows x 128 k fp32 -> bf16 (4096 float4 reads)
    #pragma unroll
    for (int i = 0; i < 16; ++i) {
        int flat = i * 256 + t;
        int r = flat >> 5, c4 = flat & 31;
        float4 v = make_float4(0.f, 0.f, 0.f, 0.f);
        if (row0 + r < N_NODES) v = *(const float4*)&x[(size_t)(row0 + r) * D_IN + c4 * 4];
        ushort4 o;
        o.x = f2bf(v.x); o.y = f2bf(v.y); o.z = f2bf(v.z); o.w = f2bf(v.w);
        *(ushort4*)&As[r * 136 + c4 * 4] = o;
    }
    // stage B^T: rows col0..col0+127 of Wt (always in-bounds; 1152 % 128 == 0)
    #pragma unroll
    for (int i = 0; i < 8; ++i) {
        int flat = i * 256 + t;
        int r = flat >> 4, c16 = flat & 15;
        int4 v = *(const int4*)&Wt[(size_t)(col0 + r) * D_IN + c16 * 8];
        *(int4*)&Bst[r * 136 + c16 * 8] = v;
    }
    __syncthreads();

    const int w = t >> 6, l = t & 63;
    const int m0 = w * 32;               // wave owns 32 rows x 128 cols
    const int lr = l & 15, lg = l >> 4;  // lane row, k-group

    f32x4 acc[2][8] = {};
    #pragma unroll
    for (int ks = 0; ks < 4; ++ks) {
        const int kb = ks * 32 + lg * 8;
        bf16x8 a0 = *(const bf16x8*)&As[(m0 + lr) * 136 + kb];
        bf16x8 a1 = *(const bf16x8*)&As[(m0 + 16 + lr) * 136 + kb];
        #pragma unroll
        for (int jn = 0; jn < 8; ++jn) {
            bf16x8 b = *(const bf16x8*)&Bst[(jn * 16 + lr) * 136 + kb];
            acc[0][jn] = __builtin_amdgcn_mfma_f32_16x16x32_bf16(a0, b, acc[0][jn], 0, 0, 0);
            acc[1][jn] = __builtin_amdgcn_mfma_f32_16x16x32_bf16(a1, b, acc[1][jn], 0, 0, 0);
        }
    }

    // epilogue: C/D layout col=lane&15, row=(lane>>4)*4+i  [m89-verified]
    #pragma unroll
    for (int im = 0; im < 2; ++im) {
        #pragma unroll
        for (int i = 0; i < 4; ++i) {
            int row = row0 + m0 + im * 16 + lg * 4 + i;
            if (row < N_NODES) {
                #pragma unroll
                for (int jn = 0; jn < 8; ++jn)
                    Ct[(size_t)row * NCT + col0 + jn * 16 + lr] = f2bf(acc[im][jn][i]);
            }
        }
    }
}

// agg: one wave per dst node; walk CSR edge list, accumulate in regs, write once.
__global__ __launch_bounds__(256) void agg_kernel(const uint2* __restrict__ epack,
                                                  const int* __restrict__ offs,
                                                  const int* __restrict__ cnt,
                                                  const unsigned short* __restrict__ Ct,
                                                  const float* __restrict__ bias,
                                                  float* __restrict__ out) {
    int node = blockIdx.x * 4 + (threadIdx.x >> 6);
    int l = threadIdx.x & 63;
    int beg = offs[node], n = cnt[node];
    float a0 = 0.f, a1 = 0.f;
    for (int k = 0; k < n; ++k) {
        uint2 p = epack[beg + k];
        unsigned v = *(const unsigned*)&Ct[(size_t)p.x + l * 2];
        float inv = __uint_as_float(p.y);
        a0 += inv * __uint_as_float((v & 0xffffu) << 16);
        a1 += inv * __uint_as_float(v & 0xffff0000u);
    }
    unsigned sv = *(const unsigned*)&Ct[(size_t)node * NCT + R_REL * O_OUT + l * 2];
    float s0 = __uint_as_float((sv & 0xffffu) << 16);
    float s1 = __uint_as_float(sv & 0xffff0000u);
    float b0 = bias[l * 2], b1 = bias[l * 2 + 1];
    float2 o;
    o.x = fmaxf(a0 + s0 + b0, 0.f);
    o.y = fmaxf(a1 + s1 + b1, 0.f);
    *(float2*)&out[(size_t)node * O_OUT + l * 2] = o;
}

extern "C" void kernel_launch(void* const* d_in, const int* in_sizes, int n_in,
                              void* d_out, int out_size, void* d_ws, size_t ws_size,
                              hipStream_t stream) {
    (void)in_sizes; (void)n_in; (void)out_size; (void)ws_size;
    const float* x       = (const float*)d_in[0];
    const float* basis_v = (const float*)d_in[1];
    const float* coeffs  = (const float*)d_in[2];
    const float* w_loop  = (const float*)d_in[3];
    const float* bias_p  = (const float*)d_in[4];
    const int*   src     = (const int*)d_in[5];
    const int*   dst     = (const int*)d_in[6];
    const int*   rel     = (const int*)d_in[7];
    float* out = (float*)d_out;

    char* ws = (char*)d_ws;
    unsigned short* Wt     = (unsigned short*)(ws);                 //     294,912 B
    unsigned short* Ct     = (unsigned short*)(ws + 524288);        // 115,200,000 B
    float*          deg    = (float*)(ws + 115724288);              //   1,600,000 B
    int*            cnt    = (int*)(ws + 117324288);                //     200,000 B
    int*            exoff  = (int*)(ws + 117524288);                //     200,000 B
    int*            offs   = (int*)(ws + 117724288);                //     200,000 B
    int*            cursor = (int*)(ws + 117924288);                //     200,000 B
    int*            bsum   = (int*)(ws + 118124288);                //       1,024 B
    int*            bbase  = (int*)(ws + 118125312);                //       1,024 B
    uint2*          epack  = (uint2*)(ws + 118126336);              //   4,800,000 B

    hipMemsetAsync(deg, 0, (size_t)R_REL * N_NODES * sizeof(float), stream);

    build_wt_kernel<<<NCT * D_IN / 256, 256, 0, stream>>>(basis_v, coeffs, w_loop, Wt);
    deg_kernel<<<(E_EDGES + 255) / 256, 256, 0, stream>>>(rel, dst, deg);
    scan1_kernel<<<NB_SCAN, 256, 0, stream>>>(deg, cnt, exoff, bsum);
    scan2_kernel<<<1, 256, 0, stream>>>(bsum, bbase);
    scan3_kernel<<<NB_SCAN, 256, 0, stream>>>(exoff, bbase, offs, cursor);
    fill_kernel<<<(E_EDGES + 255) / 256, 256, 0, stream>>>(src, dst, rel, deg, cursor, epack);
    gemm_kernel<<<dim3(NCT / 128, (N_NODES + 127) / 128), 256, 0, stream>>>(x, Wt, Ct);
    agg_kernel<<<N_NODES / 4, 256, 0, stream>>>(epack, offs, cnt, Ct, bias_p, out);
}